// Round 4
// baseline (496.417 us; speedup 1.0000x reference)
//
#include <hip/hip_runtime.h>
#include <math.h>

#define HID   1024
#define STT   4096
#define MTOK  4096   // B*L
#define LSEQ  2048
#define NCHUNK 32
#define CHUNK  64
#define VOCAB  62

typedef __attribute__((ext_vector_type(8))) short short8v;
typedef __attribute__((ext_vector_type(4))) float float4v;

typedef const __attribute__((address_space(1))) void* gptr_t;
typedef __attribute__((address_space(3))) void* lptr_t;

__device__ __forceinline__ float sigmoidf_(float x) {
    return 1.0f / (1.0f + expf(-x));
}
__device__ __forceinline__ unsigned short f2bf(float f) {
    unsigned int u = __float_as_uint(f);
    unsigned int r = (u + 0x7fffu + ((u >> 16) & 1u)) >> 16;
    return (unsigned short)r;
}
__device__ __forceinline__ float bf2f(unsigned short b) {
    return __uint_as_float(((unsigned int)b) << 16);
}

// ---------------- cast + transpose: src[R][C] f32 -> dst[C][R] bf16 ----------
__global__ __launch_bounds__(256) void cast_transpose_kernel(
    const float* __restrict__ src, unsigned short* __restrict__ dst, int R, int C)
{
    __shared__ float tile[32][33];
    int c0 = blockIdx.x * 32, r0 = blockIdx.y * 32;
    int t = threadIdx.x;
    int r = t >> 3, c4 = (t & 7) << 2;
    float4 v = *(const float4*)(src + (size_t)(r0 + r) * C + c0 + c4);
    tile[r][c4 + 0] = v.x; tile[r][c4 + 1] = v.y;
    tile[r][c4 + 2] = v.z; tile[r][c4 + 3] = v.w;
    __syncthreads();
    int oc = t >> 3;
    int orr = (t & 7) << 2;
    ushort4 o;
    o.x = f2bf(tile[orr + 0][oc]); o.y = f2bf(tile[orr + 1][oc]);
    o.z = f2bf(tile[orr + 2][oc]); o.w = f2bf(tile[orr + 3][oc]);
    *(ushort4*)(dst + (size_t)(c0 + oc) * R + r0 + orr) = o;
}

// ---------------- embedding gather + RMSNorm -> bf16 ----------------
__global__ __launch_bounds__(256) void embed_norm_kernel(
    const int* __restrict__ tokens, const float* __restrict__ embed_w,
    const float* __restrict__ norm_w, unsigned short* __restrict__ xn)
{
    int m = blockIdx.x;
    int t = threadIdx.x;
    int tok = tokens[m];
    float4 x = ((const float4*)(embed_w + (size_t)tok * HID))[t];
    float ss = x.x * x.x + x.y * x.y + x.z * x.z + x.w * x.w;
    for (int off = 32; off > 0; off >>= 1) ss += __shfl_down(ss, off);
    __shared__ float wsum[4];
    if ((t & 63) == 0) wsum[t >> 6] = ss;
    __syncthreads();
    float tot = wsum[0] + wsum[1] + wsum[2] + wsum[3];
    float scale = rsqrtf(tot / (float)HID + 1e-6f);
    float4 w4 = ((const float4*)norm_w)[t];
    ushort4 o;
    o.x = f2bf(x.x * scale * w4.x); o.y = f2bf(x.y * scale * w4.y);
    o.z = f2bf(x.z * scale * w4.z); o.w = f2bf(x.w * scale * w4.w);
    *(ushort4*)(xn + (size_t)m * HID + (t << 2)) = o;
}

// ---------------- MFMA GEMM 1: proj = xn @ in_w + in_b  (bf16 out) ----------
// 256x256 tile, BK=32, 8 waves (2M x 4N), 4-buffer depth-3 counted-vmcnt pipeline.
// LDS layout per tile: 16B chunks, chunk c = kslot*256 + row (conflict-free:
// each 16-lane frag-read group covers 256 contiguous bytes -> 2-way = free).
// A: xn bf16 [4096][1024]; B: in_wT bf16 [16384][1024]; C: proj bf16 [4096][16384]
__global__ __launch_bounds__(512, 2) void gemm_in_mfma(
    const unsigned short* __restrict__ A, const unsigned short* __restrict__ B,
    const float* __restrict__ bias, unsigned short* __restrict__ Cout)
{
    extern __shared__ unsigned short lds[];   // 4 bufs * (8192 A + 8192 B) = 128 KiB
    int tid = threadIdx.x;
    int wid = tid >> 6, lane = tid & 63;
    // XCD 2D-cell swizzle: xcd owns 4 by x 32 bx, by-fast order.
    // A-slab (4x0.5MB=2MB) + B-panel window stays L2-resident per XCD.
    int wg = blockIdx.x;
    int xcd = wg & 7, loc = wg >> 3;
    int by = ((xcd >> 1) << 2) + (loc & 3);   // 0..15
    int bx = ((xcd & 1) << 5) + (loc >> 2);   // 0..63
    int m0 = by * 256, n0 = bx * 256;
    int wm = wid >> 2, wn = wid & 3;
    int lr = lane & 15, lk = lane >> 4;

    auto stage = [&](int b, int kt) {
        unsigned short* As = lds + b * 16384;
        unsigned short* Bs = As + 8192;
        #pragma unroll
        for (int i = 0; i < 2; i++) {
            int cb = i * 512 + wid * 64;          // wave-uniform chunk base
            int c = cb + lane;
            int row = c & 255, ks = c >> 8;
            __builtin_amdgcn_global_load_lds(
                (gptr_t)(const void*)(A + (size_t)(m0 + row) * 1024 + kt + ks * 8),
                (lptr_t)(void*)(As + (size_t)cb * 8), 16, 0, 0);
            __builtin_amdgcn_global_load_lds(
                (gptr_t)(const void*)(B + (size_t)(n0 + row) * 1024 + kt + ks * 8),
                (lptr_t)(void*)(Bs + (size_t)cb * 8), 16, 0, 0);
        }
    };

    float4v acc[8][4];
    float4v z = {0.f, 0.f, 0.f, 0.f};
    #pragma unroll
    for (int i = 0; i < 8; i++)
        #pragma unroll
        for (int j = 0; j < 4; j++) acc[i][j] = z;

    const int nt = 1024 / 32;
    stage(0, 0); stage(1, 32); stage(2, 64);

    for (int t = 0; t < nt; ++t) {
        if (t + 3 < nt) stage((t + 3) & 3, (t + 3) * 32);
        if (t + 3 < nt)      asm volatile("s_waitcnt vmcnt(12)" ::: "memory");
        else if (t + 2 < nt) asm volatile("s_waitcnt vmcnt(8)" ::: "memory");
        else if (t + 1 < nt) asm volatile("s_waitcnt vmcnt(4)" ::: "memory");
        else                 asm volatile("s_waitcnt vmcnt(0)" ::: "memory");
        __builtin_amdgcn_s_barrier();
        asm volatile("" ::: "memory");
        const unsigned short* As = lds + (t & 3) * 16384;
        const unsigned short* Bs = As + 8192;
        short8v af[8], bfr[4];
        #pragma unroll
        for (int mf = 0; mf < 8; mf++)
            af[mf] = *(const short8v*)&As[((lk << 8) + wm * 128 + mf * 16 + lr) * 8];
        #pragma unroll
        for (int nf = 0; nf < 4; nf++)
            bfr[nf] = *(const short8v*)&Bs[((lk << 8) + wn * 64 + nf * 16 + lr) * 8];
        __builtin_amdgcn_s_setprio(1);
        #pragma unroll
        for (int mf = 0; mf < 8; mf++)
            #pragma unroll
            for (int nf = 0; nf < 4; nf++)
                acc[mf][nf] = __builtin_amdgcn_mfma_f32_16x16x32_bf16(
                    af[mf], bfr[nf], acc[mf][nf], 0, 0, 0);
        __builtin_amdgcn_s_setprio(0);
        asm volatile("" ::: "memory");
        __builtin_amdgcn_s_barrier();
    }

    int rbase = lk << 2;
    #pragma unroll
    for (int mf = 0; mf < 8; mf++)
        #pragma unroll
        for (int nf = 0; nf < 4; nf++) {
            int n = n0 + wn * 64 + nf * 16 + lr;
            float bv = bias[n];
            #pragma unroll
            for (int q = 0; q < 4; q++) {
                int m = m0 + wm * 128 + mf * 16 + rbase + q;
                Cout[(size_t)m * 16384 + n] = f2bf(acc[mf][nf][q] + bv);
            }
        }
}

// ---------------- MFMA GEMM 2: out = y @ out_w + out_b + residual (f32 out) --
// 128x128 tile, BK=32, 4 waves (2x2), 3-buffer depth-2 pipeline, chunk-LDS.
// A: y bf16 [4096][4096]; B: out_wT bf16 [1024][4096]; C: out f32 [4096][1024]
__global__ __launch_bounds__(256, 3) void gemm_out_mfma(
    const unsigned short* __restrict__ A, const unsigned short* __restrict__ B,
    const float* __restrict__ out_b, const int* __restrict__ tokens,
    const float* __restrict__ embed_w, float* __restrict__ Cout)
{
    extern __shared__ unsigned short lds[];   // 3 bufs * (4096 A + 4096 B) = 48 KiB
    int tid = threadIdx.x;
    int wid = tid >> 6, lane = tid & 63;
    int wg = blockIdx.x;                      // 256 WGs: 8 n-tiles x 32 m-tiles
    int swz = (wg & 7) * 32 + (wg >> 3);
    int bx = swz & 7;
    int by = swz >> 3;
    int m0 = by * 128, n0 = bx * 128;
    int wm = wid >> 1, wn = wid & 1;
    int lr = lane & 15, lk = lane >> 4;

    auto stage = [&](int b, int kt) {
        unsigned short* As = lds + b * 8192;
        unsigned short* Bs = As + 4096;
        #pragma unroll
        for (int i = 0; i < 2; i++) {
            int cb = i * 256 + wid * 64;
            int c = cb + lane;
            int row = c & 127, ks = c >> 7;
            __builtin_amdgcn_global_load_lds(
                (gptr_t)(const void*)(A + (size_t)(m0 + row) * 4096 + kt + ks * 8),
                (lptr_t)(void*)(As + (size_t)cb * 8), 16, 0, 0);
            __builtin_amdgcn_global_load_lds(
                (gptr_t)(const void*)(B + (size_t)(n0 + row) * 4096 + kt + ks * 8),
                (lptr_t)(void*)(Bs + (size_t)cb * 8), 16, 0, 0);
        }
    };

    float4v acc[4][4];
    float4v z = {0.f, 0.f, 0.f, 0.f};
    #pragma unroll
    for (int i = 0; i < 4; i++)
        #pragma unroll
        for (int j = 0; j < 4; j++) acc[i][j] = z;

    const int nt = 4096 / 32;
    stage(0, 0); stage(1, 32);

    for (int t = 0; t < nt; ++t) {
        if (t + 2 < nt) stage((t + 2) % 3, (t + 2) * 32);
        if (t + 2 < nt)      asm volatile("s_waitcnt vmcnt(8)" ::: "memory");
        else if (t + 1 < nt) asm volatile("s_waitcnt vmcnt(4)" ::: "memory");
        else                 asm volatile("s_waitcnt vmcnt(0)" ::: "memory");
        __builtin_amdgcn_s_barrier();
        asm volatile("" ::: "memory");
        const unsigned short* As = lds + (t % 3) * 8192;
        const unsigned short* Bs = As + 4096;
        short8v af[4], bfr[4];
        #pragma unroll
        for (int f = 0; f < 4; f++) {
            af[f]  = *(const short8v*)&As[((lk << 7) + wm * 64 + f * 16 + lr) * 8];
            bfr[f] = *(const short8v*)&Bs[((lk << 7) + wn * 64 + f * 16 + lr) * 8];
        }
        __builtin_amdgcn_s_setprio(1);
        #pragma unroll
        for (int mf = 0; mf < 4; mf++)
            #pragma unroll
            for (int nf = 0; nf < 4; nf++)
                acc[mf][nf] = __builtin_amdgcn_mfma_f32_16x16x32_bf16(
                    af[mf], bfr[nf], acc[mf][nf], 0, 0, 0);
        __builtin_amdgcn_s_setprio(0);
        asm volatile("" ::: "memory");
        __builtin_amdgcn_s_barrier();
    }

    int rbase = lk << 2;
    #pragma unroll
    for (int mf = 0; mf < 4; mf++) {
        #pragma unroll
        for (int q = 0; q < 4; q++) {
            int m = m0 + wm * 64 + mf * 16 + rbase + q;
            int tok = tokens[m];
            #pragma unroll
            for (int nf = 0; nf < 4; nf++) {
                int n = n0 + wn * 64 + nf * 16 + lr;
                float v = acc[mf][nf][q] + out_b[n] + embed_w[(size_t)tok * HID + n];
                Cout[(size_t)m * HID + n] = v;
            }
        }
    }
}

// ---------------- scan phase 1: per-chunk (A, H) from proj ----------------
__global__ __launch_bounds__(256) void scan_phase1(
    const unsigned short* __restrict__ proj,
    float* __restrict__ chunkA, float* __restrict__ chunkH)
{
    int bid = blockIdx.x;
    int sg = bid & 15, q = (bid >> 4) & 31, b = bid >> 9;
    int s = sg * 256 + threadIdx.x;
    int t0 = q * CHUNK;
    float Aa = 1.f, Hh = 0.f;
    const unsigned short* p = proj + (size_t)(b * LSEQ + t0) * 16384 + s;
    for (int t = 0; t < CHUNK; t++) {
        float xg = bf2f(p[0]);
        float al = bf2f(p[4096]);
        float bl = bf2f(p[8192]);
        float a = sigmoidf_(al);
        float bx = sigmoidf_(bl) * xg;
        Hh = fmaf(a, Hh, bx);
        Aa *= a;
        p += 16384;
    }
    int ch = b * STT + s;
    chunkA[ch * NCHUNK + q] = Aa;
    chunkH[ch * NCHUNK + q] = Hh;
}

__global__ __launch_bounds__(256) void scan_phase2(
    const float* __restrict__ chunkA, const float* __restrict__ chunkH,
    float* __restrict__ carry)
{
    int ch = blockIdx.x * 256 + threadIdx.x;
    float c = 0.f;
    for (int q = 0; q < NCHUNK; q++) {
        carry[ch * NCHUNK + q] = c;
        c = fmaf(chunkA[ch * NCHUNK + q], c, chunkH[ch * NCHUNK + q]);
    }
}

// ---------------- scan phase 3: h with carry, y = sig(c_l)*h (bf16) --------
__global__ __launch_bounds__(256) void scan_phase3(
    const unsigned short* __restrict__ proj, const float* __restrict__ carry,
    unsigned short* __restrict__ y)
{
    int bid = blockIdx.x;
    int sg = bid & 15, q = (bid >> 4) & 31, b = bid >> 9;
    int s = sg * 256 + threadIdx.x;
    int t0 = q * CHUNK;
    int ch = b * STT + s;
    float h = carry[ch * NCHUNK + q];
    const unsigned short* p = proj + (size_t)(b * LSEQ + t0) * 16384 + s;
    unsigned short* yp = y + (size_t)(b * LSEQ + t0) * STT + s;
    for (int t = 0; t < CHUNK; t++) {
        float xg = bf2f(p[0]);
        float al = bf2f(p[4096]);
        float bl = bf2f(p[8192]);
        float cl = bf2f(p[12288]);
        float a = sigmoidf_(al);
        float bx = sigmoidf_(bl) * xg;
        h = fmaf(a, h, bx);
        *yp = f2bf(sigmoidf_(cl) * h);
        p += 16384; yp += STT;
    }
}

// ---------------- head GEMM ----------------
__global__ __launch_bounds__(64) void head_kernel(
    const float* __restrict__ out, const float* __restrict__ head_w,
    const float* __restrict__ head_b, float* __restrict__ logits)
{
    __shared__ float row[HID];
    int m = blockIdx.x;
    int t = threadIdx.x;
    for (int i = t; i < HID / 4; i += 64)
        ((float4*)row)[i] = ((const float4*)(out + (size_t)m * HID))[i];
    __syncthreads();
    if (t < VOCAB) {
        float s = head_b[t];
        #pragma unroll 8
        for (int k = 0; k < HID; k++)
            s = fmaf(row[k], head_w[k * VOCAB + t], s);
        logits[m * VOCAB + t] = s;
    }
}

extern "C" void kernel_launch(void* const* d_in, const int* in_sizes, int n_in,
                              void* d_out, int out_size, void* d_ws, size_t ws_size,
                              hipStream_t stream) {
    const int*   tokens  = (const int*)d_in[0];
    const float* embed_w = (const float*)d_in[1];
    const float* norm_w  = (const float*)d_in[2];
    const float* in_w    = (const float*)d_in[3];
    const float* in_b    = (const float*)d_in[4];
    const float* out_w   = (const float*)d_in[5];
    const float* out_b   = (const float*)d_in[6];
    const float* head_w  = (const float*)d_in[7];
    const float* head_b  = (const float*)d_in[8];
    float* logits = (float*)d_out;

    char* w = (char*)d_ws;
    unsigned short* proj   = (unsigned short*)w;                    // 128 MiB
    unsigned short* y      = (unsigned short*)(w + 134217728);      // 32 MiB
    unsigned short* in_wT  = (unsigned short*)(w + 167772160);      // 32 MiB
    float*          outbuf = (float*)(w + 167772160);               // reuses in_wT (16 MiB)
    unsigned short* xn     = (unsigned short*)(w + 201326592);      // 8 MiB
    unsigned short* out_wT = (unsigned short*)(w + 201326592);      // reuses xn (8 MiB)
    float* chunkA = (float*)(w + 209715200);
    float* chunkH = chunkA + 8192 * NCHUNK;
    float* carry  = chunkH + 8192 * NCHUNK;

    hipLaunchKernelGGL(cast_transpose_kernel, dim3(16384 / 32, 1024 / 32), dim3(256), 0, stream,
                       in_w, in_wT, 1024, 16384);
    hipLaunchKernelGGL(embed_norm_kernel, dim3(MTOK), dim3(256), 0, stream,
                       tokens, embed_w, norm_w, xn);
    hipLaunchKernelGGL(gemm_in_mfma, dim3(1024), dim3(512), 131072, stream,
                       xn, in_wT, in_b, proj);
    hipLaunchKernelGGL(scan_phase1, dim3(1024), dim3(256), 0, stream,
                       proj, chunkA, chunkH);
    hipLaunchKernelGGL(scan_phase2, dim3(32), dim3(256), 0, stream,
                       chunkA, chunkH, carry);
    hipLaunchKernelGGL(scan_phase3, dim3(1024), dim3(256), 0, stream,
                       proj, carry, y);
    hipLaunchKernelGGL(cast_transpose_kernel, dim3(1024 / 32, 4096 / 32), dim3(256), 0, stream,
                       out_w, out_wT, 4096, 1024);
    hipLaunchKernelGGL(gemm_out_mfma, dim3(256), dim3(256), 49152, stream,
                       y, out_wT, out_b, tokens, embed_w, outbuf);
    hipLaunchKernelGGL(head_kernel, dim3(MTOK), dim3(64), 0, stream,
                       outbuf, head_w, head_b, logits);
}

// Round 5
// 369.960 us; speedup vs baseline: 1.3418x; 1.3418x over previous
//
#include <hip/hip_runtime.h>
#include <math.h>

#define HID   1024
#define STT   4096
#define MTOK  4096   // B*L
#define LSEQ  2048
#define NCHUNK 32
#define CHUNK  64
#define VOCAB  62

typedef __attribute__((ext_vector_type(8))) short short8v;
typedef __attribute__((ext_vector_type(4))) float float4v;

typedef const __attribute__((address_space(1))) void* gptr_t;
typedef __attribute__((address_space(3))) void* lptr_t;

__device__ __forceinline__ float sigmoidf_(float x) {
    return 1.0f / (1.0f + expf(-x));
}
__device__ __forceinline__ unsigned short f2bf(float f) {
    unsigned int u = __float_as_uint(f);
    unsigned int r = (u + 0x7fffu + ((u >> 16) & 1u)) >> 16;
    return (unsigned short)r;
}
__device__ __forceinline__ float bf2f(unsigned short b) {
    return __uint_as_float(((unsigned int)b) << 16);
}

// ---------------- cast + transpose: src[R][C] f32 -> dst[C][R] bf16 ----------
__global__ __launch_bounds__(256) void cast_transpose_kernel(
    const float* __restrict__ src, unsigned short* __restrict__ dst, int R, int C)
{
    __shared__ float tile[32][33];
    int c0 = blockIdx.x * 32, r0 = blockIdx.y * 32;
    int t = threadIdx.x;
    int r = t >> 3, c4 = (t & 7) << 2;
    float4 v = *(const float4*)(src + (size_t)(r0 + r) * C + c0 + c4);
    tile[r][c4 + 0] = v.x; tile[r][c4 + 1] = v.y;
    tile[r][c4 + 2] = v.z; tile[r][c4 + 3] = v.w;
    __syncthreads();
    int oc = t >> 3;
    int orr = (t & 7) << 2;
    ushort4 o;
    o.x = f2bf(tile[orr + 0][oc]); o.y = f2bf(tile[orr + 1][oc]);
    o.z = f2bf(tile[orr + 2][oc]); o.w = f2bf(tile[orr + 3][oc]);
    *(ushort4*)(dst + (size_t)(c0 + oc) * R + r0 + orr) = o;
}

// ---------------- embedding gather + RMSNorm -> bf16 ----------------
__global__ __launch_bounds__(256) void embed_norm_kernel(
    const int* __restrict__ tokens, const float* __restrict__ embed_w,
    const float* __restrict__ norm_w, unsigned short* __restrict__ xn)
{
    int m = blockIdx.x;
    int t = threadIdx.x;
    int tok = tokens[m];
    float4 x = ((const float4*)(embed_w + (size_t)tok * HID))[t];
    float ss = x.x * x.x + x.y * x.y + x.z * x.z + x.w * x.w;
    for (int off = 32; off > 0; off >>= 1) ss += __shfl_down(ss, off);
    __shared__ float wsum[4];
    if ((t & 63) == 0) wsum[t >> 6] = ss;
    __syncthreads();
    float tot = wsum[0] + wsum[1] + wsum[2] + wsum[3];
    float scale = rsqrtf(tot / (float)HID + 1e-6f);
    float4 w4 = ((const float4*)norm_w)[t];
    ushort4 o;
    o.x = f2bf(x.x * scale * w4.x); o.y = f2bf(x.y * scale * w4.y);
    o.z = f2bf(x.z * scale * w4.z); o.w = f2bf(x.w * scale * w4.w);
    *(ushort4*)(xn + (size_t)m * HID + (t << 2)) = o;
}

// ---------------- MFMA GEMM 1: proj = xn @ in_w + in_b  (bf16 out) ----------
// 256x256 tile, BK=32, 8 waves (2M x 4N), 4-buffer depth-3 counted-vmcnt pipeline.
// LDS: 16B chunks, p = row*4 + (ks ^ ((row>>1)&3)).
//   staging: row-fast chunk order -> global src coalesced (16 rows x 64B / instr);
//   frag read (lr=0..15, lk fixed): bank class 4*(lr&1) + (lk^((lr>>1)&3))
//   covers all 8 classes exactly 2x -> 2-way = conflict-free.
__global__ __launch_bounds__(512, 2) void gemm_in_mfma(
    const unsigned short* __restrict__ A, const unsigned short* __restrict__ B,
    const float* __restrict__ bias, unsigned short* __restrict__ Cout)
{
    extern __shared__ unsigned short lds[];   // 4 bufs * (8192 A + 8192 B) = 128 KiB
    int tid = threadIdx.x;
    int wid = tid >> 6, lane = tid & 63;
    // XCD 2D-cell swizzle: xcd owns 4 by x 32 bx (by-fast) -> L2-resident panels
    int wg = blockIdx.x;
    int xcd = wg & 7, loc = wg >> 3;
    int by = ((xcd >> 1) << 2) + (loc & 3);   // 0..15
    int bx = ((xcd & 1) << 5) + (loc >> 2);   // 0..63
    int m0 = by * 256, n0 = bx * 256;
    int wm = wid >> 2, wn = wid & 3;
    int lr = lane & 15, lk = lane >> 4;

    auto stage = [&](int b, int kt) {
        unsigned short* As = lds + b * 16384;
        unsigned short* Bs = As + 8192;
        #pragma unroll
        for (int i = 0; i < 2; i++) {
            int cb = i * 512 + wid * 64;          // wave-uniform chunk base
            int p = cb + lane;                    // LDS chunk this lane fills
            int row = p >> 2;
            int ks = (p & 3) ^ ((row >> 1) & 3);  // inverse swizzle (XOR involution)
            __builtin_amdgcn_global_load_lds(
                (gptr_t)(const void*)(A + (size_t)(m0 + row) * 1024 + kt + ks * 8),
                (lptr_t)(void*)(As + (size_t)cb * 8), 16, 0, 0);
            __builtin_amdgcn_global_load_lds(
                (gptr_t)(const void*)(B + (size_t)(n0 + row) * 1024 + kt + ks * 8),
                (lptr_t)(void*)(Bs + (size_t)cb * 8), 16, 0, 0);
        }
    };

    float4v acc[8][4];
    float4v z = {0.f, 0.f, 0.f, 0.f};
    #pragma unroll
    for (int i = 0; i < 8; i++)
        #pragma unroll
        for (int j = 0; j < 4; j++) acc[i][j] = z;

    const int nt = 1024 / 32;
    stage(0, 0); stage(1, 32); stage(2, 64);

    // per-lane swizzled k-slot: rows in a frag group start at mult of 16,
    // so (row>>1)&3 == (lr>>1)&3 -> constant per lane across all frags
    int ksw = lk ^ ((lr >> 1) & 3);
    int aoff = lr * 4 + ksw;                      // chunk offset within row-block

    for (int t = 0; t < nt; ++t) {
        if (t + 3 < nt) stage((t + 3) & 3, (t + 3) * 32);
        if (t + 3 < nt)      asm volatile("s_waitcnt vmcnt(12)" ::: "memory");
        else if (t + 2 < nt) asm volatile("s_waitcnt vmcnt(8)" ::: "memory");
        else if (t + 1 < nt) asm volatile("s_waitcnt vmcnt(4)" ::: "memory");
        else                 asm volatile("s_waitcnt vmcnt(0)" ::: "memory");
        __builtin_amdgcn_s_barrier();
        asm volatile("" ::: "memory");
        const unsigned short* As = lds + (t & 3) * 16384;
        const unsigned short* Bs = As + 8192;
        short8v af[8], bfr[4];
        #pragma unroll
        for (int mf = 0; mf < 8; mf++)
            af[mf] = *(const short8v*)&As[((wm * 128 + mf * 16) * 4 + aoff) * 8];
        #pragma unroll
        for (int nf = 0; nf < 4; nf++)
            bfr[nf] = *(const short8v*)&Bs[((wn * 64 + nf * 16) * 4 + aoff) * 8];
        __builtin_amdgcn_s_setprio(1);
        #pragma unroll
        for (int mf = 0; mf < 8; mf++)
            #pragma unroll
            for (int nf = 0; nf < 4; nf++)
                acc[mf][nf] = __builtin_amdgcn_mfma_f32_16x16x32_bf16(
                    af[mf], bfr[nf], acc[mf][nf], 0, 0, 0);
        __builtin_amdgcn_s_setprio(0);
        asm volatile("" ::: "memory");
        __builtin_amdgcn_s_barrier();
    }

    int rbase = lk << 2;
    #pragma unroll
    for (int mf = 0; mf < 8; mf++)
        #pragma unroll
        for (int nf = 0; nf < 4; nf++) {
            int n = n0 + wn * 64 + nf * 16 + lr;
            float bv = bias[n];
            #pragma unroll
            for (int q = 0; q < 4; q++) {
                int m = m0 + wm * 128 + mf * 16 + rbase + q;
                Cout[(size_t)m * 16384 + n] = f2bf(acc[mf][nf][q] + bv);
            }
        }
}

// ---------------- MFMA GEMM 2: out = y @ out_w + out_b + residual (f32 out) --
// 128x128 tile, BK=32, 4 waves (2x2), 3-buffer depth-2 pipeline, same swizzle.
__global__ __launch_bounds__(256, 3) void gemm_out_mfma(
    const unsigned short* __restrict__ A, const unsigned short* __restrict__ B,
    const float* __restrict__ out_b, const int* __restrict__ tokens,
    const float* __restrict__ embed_w, float* __restrict__ Cout)
{
    extern __shared__ unsigned short lds[];   // 3 bufs * (4096 A + 4096 B) = 48 KiB
    int tid = threadIdx.x;
    int wid = tid >> 6, lane = tid & 63;
    int wg = blockIdx.x;                      // 256 WGs: 8 n-tiles x 32 m-tiles
    int swz = (wg & 7) * 32 + (wg >> 3);
    int bx = swz & 7;
    int by = swz >> 3;
    int m0 = by * 128, n0 = bx * 128;
    int wm = wid >> 1, wn = wid & 1;
    int lr = lane & 15, lk = lane >> 4;

    auto stage = [&](int b, int kt) {
        unsigned short* As = lds + b * 8192;
        unsigned short* Bs = As + 4096;
        #pragma unroll
        for (int i = 0; i < 2; i++) {
            int cb = i * 256 + wid * 64;
            int p = cb + lane;
            int row = p >> 2;
            int ks = (p & 3) ^ ((row >> 1) & 3);
            __builtin_amdgcn_global_load_lds(
                (gptr_t)(const void*)(A + (size_t)(m0 + row) * 4096 + kt + ks * 8),
                (lptr_t)(void*)(As + (size_t)cb * 8), 16, 0, 0);
            __builtin_amdgcn_global_load_lds(
                (gptr_t)(const void*)(B + (size_t)(n0 + row) * 4096 + kt + ks * 8),
                (lptr_t)(void*)(Bs + (size_t)cb * 8), 16, 0, 0);
        }
    };

    float4v acc[4][4];
    float4v z = {0.f, 0.f, 0.f, 0.f};
    #pragma unroll
    for (int i = 0; i < 4; i++)
        #pragma unroll
        for (int j = 0; j < 4; j++) acc[i][j] = z;

    const int nt = 4096 / 32;
    stage(0, 0); stage(1, 32);

    int ksw = lk ^ ((lr >> 1) & 3);
    int aoff = lr * 4 + ksw;

    for (int t = 0; t < nt; ++t) {
        if (t + 2 < nt) stage((t + 2) % 3, (t + 2) * 32);
        if (t + 2 < nt)      asm volatile("s_waitcnt vmcnt(8)" ::: "memory");
        else if (t + 1 < nt) asm volatile("s_waitcnt vmcnt(4)" ::: "memory");
        else                 asm volatile("s_waitcnt vmcnt(0)" ::: "memory");
        __builtin_amdgcn_s_barrier();
        asm volatile("" ::: "memory");
        const unsigned short* As = lds + (t % 3) * 8192;
        const unsigned short* Bs = As + 4096;
        short8v af[4], bfr[4];
        #pragma unroll
        for (int f = 0; f < 4; f++) {
            af[f]  = *(const short8v*)&As[((wm * 64 + f * 16) * 4 + aoff) * 8];
            bfr[f] = *(const short8v*)&Bs[((wn * 64 + f * 16) * 4 + aoff) * 8];
        }
        __builtin_amdgcn_s_setprio(1);
        #pragma unroll
        for (int mf = 0; mf < 4; mf++)
            #pragma unroll
            for (int nf = 0; nf < 4; nf++)
                acc[mf][nf] = __builtin_amdgcn_mfma_f32_16x16x32_bf16(
                    af[mf], bfr[nf], acc[mf][nf], 0, 0, 0);
        __builtin_amdgcn_s_setprio(0);
        asm volatile("" ::: "memory");
        __builtin_amdgcn_s_barrier();
    }

    int rbase = lk << 2;
    #pragma unroll
    for (int mf = 0; mf < 4; mf++) {
        #pragma unroll
        for (int q = 0; q < 4; q++) {
            int m = m0 + wm * 64 + mf * 16 + rbase + q;
            int tok = tokens[m];
            #pragma unroll
            for (int nf = 0; nf < 4; nf++) {
                int n = n0 + wn * 64 + nf * 16 + lr;
                float v = acc[mf][nf][q] + out_b[n] + embed_w[(size_t)tok * HID + n];
                Cout[(size_t)m * HID + n] = v;
            }
        }
    }
}

// ---------------- scan phase 1: per-chunk (A, H) from proj ----------------
__global__ __launch_bounds__(256) void scan_phase1(
    const unsigned short* __restrict__ proj,
    float* __restrict__ chunkA, float* __restrict__ chunkH)
{
    int bid = blockIdx.x;
    int sg = bid & 15, q = (bid >> 4) & 31, b = bid >> 9;
    int s = sg * 256 + threadIdx.x;
    int t0 = q * CHUNK;
    float Aa = 1.f, Hh = 0.f;
    const unsigned short* p = proj + (size_t)(b * LSEQ + t0) * 16384 + s;
    for (int t = 0; t < CHUNK; t++) {
        float xg = bf2f(p[0]);
        float al = bf2f(p[4096]);
        float bl = bf2f(p[8192]);
        float a = sigmoidf_(al);
        float bx = sigmoidf_(bl) * xg;
        Hh = fmaf(a, Hh, bx);
        Aa *= a;
        p += 16384;
    }
    int ch = b * STT + s;
    chunkA[ch * NCHUNK + q] = Aa;
    chunkH[ch * NCHUNK + q] = Hh;
}

__global__ __launch_bounds__(256) void scan_phase2(
    const float* __restrict__ chunkA, const float* __restrict__ chunkH,
    float* __restrict__ carry)
{
    int ch = blockIdx.x * 256 + threadIdx.x;
    float c = 0.f;
    for (int q = 0; q < NCHUNK; q++) {
        carry[ch * NCHUNK + q] = c;
        c = fmaf(chunkA[ch * NCHUNK + q], c, chunkH[ch * NCHUNK + q]);
    }
}

// ---------------- scan phase 3: h with carry, y = sig(c_l)*h (bf16) --------
__global__ __launch_bounds__(256) void scan_phase3(
    const unsigned short* __restrict__ proj, const float* __restrict__ carry,
    unsigned short* __restrict__ y)
{
    int bid = blockIdx.x;
    int sg = bid & 15, q = (bid >> 4) & 31, b = bid >> 9;
    int s = sg * 256 + threadIdx.x;
    int t0 = q * CHUNK;
    int ch = b * STT + s;
    float h = carry[ch * NCHUNK + q];
    const unsigned short* p = proj + (size_t)(b * LSEQ + t0) * 16384 + s;
    unsigned short* yp = y + (size_t)(b * LSEQ + t0) * STT + s;
    for (int t = 0; t < CHUNK; t++) {
        float xg = bf2f(p[0]);
        float al = bf2f(p[4096]);
        float bl = bf2f(p[8192]);
        float cl = bf2f(p[12288]);
        float a = sigmoidf_(al);
        float bx = sigmoidf_(bl) * xg;
        h = fmaf(a, h, bx);
        *yp = f2bf(sigmoidf_(cl) * h);
        p += 16384; yp += STT;
    }
}

// ---------------- head GEMM ----------------
__global__ __launch_bounds__(64) void head_kernel(
    const float* __restrict__ out, const float* __restrict__ head_w,
    const float* __restrict__ head_b, float* __restrict__ logits)
{
    __shared__ float row[HID];
    int m = blockIdx.x;
    int t = threadIdx.x;
    for (int i = t; i < HID / 4; i += 64)
        ((float4*)row)[i] = ((const float4*)(out + (size_t)m * HID))[i];
    __syncthreads();
    if (t < VOCAB) {
        float s = head_b[t];
        #pragma unroll 8
        for (int k = 0; k < HID; k++)
            s = fmaf(row[k], head_w[k * VOCAB + t], s);
        logits[m * VOCAB + t] = s;
    }
}

extern "C" void kernel_launch(void* const* d_in, const int* in_sizes, int n_in,
                              void* d_out, int out_size, void* d_ws, size_t ws_size,
                              hipStream_t stream) {
    const int*   tokens  = (const int*)d_in[0];
    const float* embed_w = (const float*)d_in[1];
    const float* norm_w  = (const float*)d_in[2];
    const float* in_w    = (const float*)d_in[3];
    const float* in_b    = (const float*)d_in[4];
    const float* out_w   = (const float*)d_in[5];
    const float* out_b   = (const float*)d_in[6];
    const float* head_w  = (const float*)d_in[7];
    const float* head_b  = (const float*)d_in[8];
    float* logits = (float*)d_out;

    char* w = (char*)d_ws;
    unsigned short* proj   = (unsigned short*)w;                    // 128 MiB
    unsigned short* y      = (unsigned short*)(w + 134217728);      // 32 MiB
    unsigned short* in_wT  = (unsigned short*)(w + 167772160);      // 32 MiB
    float*          outbuf = (float*)(w + 167772160);               // reuses in_wT (16 MiB)
    unsigned short* xn     = (unsigned short*)(w + 201326592);      // 8 MiB
    unsigned short* out_wT = (unsigned short*)(w + 201326592);      // reuses xn (8 MiB)
    float* chunkA = (float*)(w + 209715200);
    float* chunkH = chunkA + 8192 * NCHUNK;
    float* carry  = chunkH + 8192 * NCHUNK;

    hipLaunchKernelGGL(cast_transpose_kernel, dim3(16384 / 32, 1024 / 32), dim3(256), 0, stream,
                       in_w, in_wT, 1024, 16384);
    hipLaunchKernelGGL(embed_norm_kernel, dim3(MTOK), dim3(256), 0, stream,
                       tokens, embed_w, norm_w, xn);
    hipLaunchKernelGGL(gemm_in_mfma, dim3(1024), dim3(512), 131072, stream,
                       xn, in_wT, in_b, proj);
    hipLaunchKernelGGL(scan_phase1, dim3(1024), dim3(256), 0, stream,
                       proj, chunkA, chunkH);
    hipLaunchKernelGGL(scan_phase2, dim3(32), dim3(256), 0, stream,
                       chunkA, chunkH, carry);
    hipLaunchKernelGGL(scan_phase3, dim3(1024), dim3(256), 0, stream,
                       proj, carry, y);
    hipLaunchKernelGGL(cast_transpose_kernel, dim3(1024 / 32, 4096 / 32), dim3(256), 0, stream,
                       out_w, out_wT, 4096, 1024);
    hipLaunchKernelGGL(gemm_out_mfma, dim3(256), dim3(256), 49152, stream,
                       y, out_wT, out_b, tokens, embed_w, outbuf);
    hipLaunchKernelGGL(head_kernel, dim3(MTOK), dim3(64), 0, stream,
                       outbuf, head_w, head_b, logits);
}

// Round 6
// 362.371 us; speedup vs baseline: 1.3699x; 1.0209x over previous
//
#include <hip/hip_runtime.h>
#include <math.h>

#define HID   1024
#define STT   4096
#define MTOK  4096   // B*L
#define LSEQ  2048
#define NCHUNK 32
#define CHUNK  64
#define VOCAB  62

typedef __attribute__((ext_vector_type(8))) short short8v;
typedef __attribute__((ext_vector_type(4))) float float4v;

typedef const __attribute__((address_space(1))) void* gptr_t;
typedef __attribute__((address_space(3))) void* lptr_t;

__device__ __forceinline__ float sigmoidf_(float x) {
    return 1.0f / (1.0f + expf(-x));
}
__device__ __forceinline__ unsigned short f2bf(float f) {
    unsigned int u = __float_as_uint(f);
    unsigned int r = (u + 0x7fffu + ((u >> 16) & 1u)) >> 16;
    return (unsigned short)r;
}
__device__ __forceinline__ float bf2f(unsigned short b) {
    return __uint_as_float(((unsigned int)b) << 16);
}

// ---------------- cast + transpose: src[R][C] f32 -> dst[C][R] bf16 ----------
__global__ __launch_bounds__(256) void cast_transpose_kernel(
    const float* __restrict__ src, unsigned short* __restrict__ dst, int R, int C)
{
    __shared__ float tile[32][33];
    int c0 = blockIdx.x * 32, r0 = blockIdx.y * 32;
    int t = threadIdx.x;
    int r = t >> 3, c4 = (t & 7) << 2;
    float4 v = *(const float4*)(src + (size_t)(r0 + r) * C + c0 + c4);
    tile[r][c4 + 0] = v.x; tile[r][c4 + 1] = v.y;
    tile[r][c4 + 2] = v.z; tile[r][c4 + 3] = v.w;
    __syncthreads();
    int oc = t >> 3;
    int orr = (t & 7) << 2;
    ushort4 o;
    o.x = f2bf(tile[orr + 0][oc]); o.y = f2bf(tile[orr + 1][oc]);
    o.z = f2bf(tile[orr + 2][oc]); o.w = f2bf(tile[orr + 3][oc]);
    *(ushort4*)(dst + (size_t)(c0 + oc) * R + r0 + orr) = o;
}

// ---------------- embedding gather + RMSNorm -> bf16 ----------------
__global__ __launch_bounds__(256) void embed_norm_kernel(
    const int* __restrict__ tokens, const float* __restrict__ embed_w,
    const float* __restrict__ norm_w, unsigned short* __restrict__ xn)
{
    int m = blockIdx.x;
    int t = threadIdx.x;
    int tok = tokens[m];
    float4 x = ((const float4*)(embed_w + (size_t)tok * HID))[t];
    float ss = x.x * x.x + x.y * x.y + x.z * x.z + x.w * x.w;
    for (int off = 32; off > 0; off >>= 1) ss += __shfl_down(ss, off);
    __shared__ float wsum[4];
    if ((t & 63) == 0) wsum[t >> 6] = ss;
    __syncthreads();
    float tot = wsum[0] + wsum[1] + wsum[2] + wsum[3];
    float scale = rsqrtf(tot / (float)HID + 1e-6f);
    float4 w4 = ((const float4*)norm_w)[t];
    ushort4 o;
    o.x = f2bf(x.x * scale * w4.x); o.y = f2bf(x.y * scale * w4.y);
    o.z = f2bf(x.z * scale * w4.z); o.w = f2bf(x.w * scale * w4.w);
    *(ushort4*)(xn + (size_t)m * HID + (t << 2)) = o;
}

// ---------------- MFMA GEMM 1: proj = xn @ in_w + in_b  (bf16 out) ----------
// 256x256 tile, BK=64, 8 waves (2M x 4N), 2 LDS buffers, 8-phase counted-vmcnt
// schedule (4 phases/K-tile): per phase stage 1 half-tile (2 gload_lds/thread),
// vmcnt(6) only on kk-boundary phases (never 0 in the loop), barrier,
// ds_read frags, setprio(1) 16 MFMA setprio(0), barrier.
// LDS per buffer: A[2kk][256rows][4 chunks] + B same; chunk = row*4+(ks^((row>>1)&3))
// (coalesced stage: 16 rows x 64B per instr; frag reads 2-way = conflict-free).
__global__ __launch_bounds__(512, 2) void gemm_in_mfma(
    const unsigned short* __restrict__ A, const unsigned short* __restrict__ B,
    const float* __restrict__ bias, unsigned short* __restrict__ Cout)
{
    extern __shared__ unsigned short lds[];   // 2 bufs * 32768 = 128 KiB
    int tid = threadIdx.x;
    int wid = tid >> 6, lane = tid & 63;
    // XCD 2D-cell swizzle: xcd owns 4 by x 32 bx (by-fast) -> L2-resident panels
    int wg = blockIdx.x;
    int xcd = wg & 7, loc = wg >> 3;
    int by = ((xcd >> 1) << 2) + (loc & 3);   // 0..15
    int bx = ((xcd & 1) << 5) + (loc >> 2);   // 0..63
    int m0 = by * 256, n0 = bx * 256;
    int wm = wid >> 2, wn = wid & 3;
    int lr = lane & 15, lk = lane >> 4;

    // staging lane mapping (per kk-half: 256 rows x 4 chunks)
    int cb0 = wid * 64, cb1 = 512 + wid * 64;     // wave-uniform chunk bases
    int p0 = cb0 + lane, p1 = cb1 + lane;
    int row0 = p0 >> 2, ks0 = (p0 & 3) ^ ((row0 >> 1) & 3);
    int row1 = p1 >> 2, ks1 = (p1 & 3) ^ ((row1 >> 1) & 3);

#define STAGE_HALF(SRC, base0, dstbuf, kt, kk) do {                              \
    unsigned short* _d = (dstbuf) + (kk) * 8192;                                 \
    __builtin_amdgcn_global_load_lds(                                            \
        (gptr_t)(const void*)((SRC) + (size_t)((base0) + row0) * 1024 +          \
                              (kt) * 64 + (kk) * 32 + ks0 * 8),                  \
        (lptr_t)(void*)(_d + (size_t)cb0 * 8), 16, 0, 0);                        \
    __builtin_amdgcn_global_load_lds(                                            \
        (gptr_t)(const void*)((SRC) + (size_t)((base0) + row1) * 1024 +          \
                              (kt) * 64 + (kk) * 32 + ks1 * 8),                  \
        (lptr_t)(void*)(_d + (size_t)cb1 * 8), 16, 0, 0);                        \
} while (0)

    float4v acc[8][4];
    float4v z = {0.f, 0.f, 0.f, 0.f};
    #pragma unroll
    for (int i = 0; i < 8; i++)
        #pragma unroll
        for (int j = 0; j < 4; j++) acc[i][j] = z;

    int ksw = lk ^ ((lr >> 1) & 3);

#define PHASE_COMPUTE(Asrc, Bsrc, kk, nh, LOAD_AF) do {                          \
    if (LOAD_AF) {                                                               \
        _Pragma("unroll")                                                        \
        for (int mf = 0; mf < 8; mf++)                                           \
            af[mf] = *(const short8v*)&(Asrc)[(kk) * 8192 +                      \
                (((wm * 128 + mf * 16 + lr) << 2) + ksw) * 8];                   \
    }                                                                            \
    short8v bf0 = *(const short8v*)&(Bsrc)[(kk) * 8192 +                         \
        (((wn * 64 + (2 * (nh)) * 16 + lr) << 2) + ksw) * 8];                    \
    short8v bf1 = *(const short8v*)&(Bsrc)[(kk) * 8192 +                         \
        (((wn * 64 + (2 * (nh) + 1) * 16 + lr) << 2) + ksw) * 8];                \
    __builtin_amdgcn_s_setprio(1);                                               \
    _Pragma("unroll")                                                            \
    for (int mf = 0; mf < 8; mf++) {                                             \
        acc[mf][2 * (nh)]     = __builtin_amdgcn_mfma_f32_16x16x32_bf16(         \
            af[mf], bf0, acc[mf][2 * (nh)], 0, 0, 0);                            \
        acc[mf][2 * (nh) + 1] = __builtin_amdgcn_mfma_f32_16x16x32_bf16(         \
            af[mf], bf1, acc[mf][2 * (nh) + 1], 0, 0, 0);                        \
    }                                                                            \
    __builtin_amdgcn_s_setprio(0);                                               \
} while (0)

    // prologue: stage K-tile 0 fully (order: Ak0, Bk0, Ak1, Bk1)
    STAGE_HALF(A, m0, lds, 0, 0);
    STAGE_HALF(B, n0, lds + 16384, 0, 0);
    STAGE_HALF(A, m0, lds, 0, 1);
    STAGE_HALF(B, n0, lds + 16384, 0, 1);

    for (int kt = 0; kt < 16; ++kt) {
        const int rd = kt & 1;
        const unsigned short* As = lds + rd * 32768;
        const unsigned short* Bs = As + 16384;
        unsigned short* Aw = lds + (rd ^ 1) * 32768;
        unsigned short* Bw = Aw + 16384;
        int ktn = kt < 15 ? kt + 1 : 15;   // clamped dup-stage on last tile (harmless)
        short8v af[8];
        // ---- phase 0: stage next Ak0; wait for this tile's k0 halves
        STAGE_HALF(A, m0, Aw, ktn, 0);
        asm volatile("s_waitcnt vmcnt(6)" ::: "memory");
        __builtin_amdgcn_s_barrier();
        asm volatile("" ::: "memory");
        PHASE_COMPUTE(As, Bs, 0, 0, 1);
        asm volatile("" ::: "memory");
        __builtin_amdgcn_s_barrier();
        // ---- phase 1: stage next Bk0
        STAGE_HALF(B, n0, Bw, ktn, 0);
        __builtin_amdgcn_s_barrier();
        asm volatile("" ::: "memory");
        PHASE_COMPUTE(As, Bs, 0, 1, 0);
        asm volatile("" ::: "memory");
        __builtin_amdgcn_s_barrier();
        // ---- phase 2: stage next Ak1; wait for this tile's k1 halves
        STAGE_HALF(A, m0, Aw, ktn, 1);
        asm volatile("s_waitcnt vmcnt(6)" ::: "memory");
        __builtin_amdgcn_s_barrier();
        asm volatile("" ::: "memory");
        PHASE_COMPUTE(As, Bs, 1, 0, 1);
        asm volatile("" ::: "memory");
        __builtin_amdgcn_s_barrier();
        // ---- phase 3: stage next Bk1
        STAGE_HALF(B, n0, Bw, ktn, 1);
        __builtin_amdgcn_s_barrier();
        asm volatile("" ::: "memory");
        PHASE_COMPUTE(As, Bs, 1, 1, 0);
        asm volatile("" ::: "memory");
        __builtin_amdgcn_s_barrier();
    }

    int rbase = lk << 2;
    #pragma unroll
    for (int mf = 0; mf < 8; mf++)
        #pragma unroll
        for (int nf = 0; nf < 4; nf++) {
            int n = n0 + wn * 64 + nf * 16 + lr;
            float bv = bias[n];
            #pragma unroll
            for (int q = 0; q < 4; q++) {
                int m = m0 + wm * 128 + mf * 16 + rbase + q;
                Cout[(size_t)m * 16384 + n] = f2bf(acc[mf][nf][q] + bv);
            }
        }
#undef STAGE_HALF
#undef PHASE_COMPUTE
}

// ---------------- MFMA GEMM 2: out = y @ out_w + out_b + residual (f32 out) --
// 128x128 tile, BK=32, 4 waves (2x2), 3-buffer depth-2 pipeline, chunk swizzle.
__global__ __launch_bounds__(256, 3) void gemm_out_mfma(
    const unsigned short* __restrict__ A, const unsigned short* __restrict__ B,
    const float* __restrict__ out_b, const int* __restrict__ tokens,
    const float* __restrict__ embed_w, float* __restrict__ Cout)
{
    extern __shared__ unsigned short lds[];   // 3 bufs * (4096 A + 4096 B) = 48 KiB
    int tid = threadIdx.x;
    int wid = tid >> 6, lane = tid & 63;
    int wg = blockIdx.x;                      // 256 WGs: 8 n-tiles x 32 m-tiles
    int swz = (wg & 7) * 32 + (wg >> 3);
    int bx = swz & 7;
    int by = swz >> 3;
    int m0 = by * 128, n0 = bx * 128;
    int wm = wid >> 1, wn = wid & 1;
    int lr = lane & 15, lk = lane >> 4;

    auto stage = [&](int b, int kt) {
        unsigned short* As = lds + b * 8192;
        unsigned short* Bs = As + 4096;
        #pragma unroll
        for (int i = 0; i < 2; i++) {
            int cb = i * 256 + wid * 64;
            int p = cb + lane;
            int row = p >> 2;
            int ks = (p & 3) ^ ((row >> 1) & 3);
            __builtin_amdgcn_global_load_lds(
                (gptr_t)(const void*)(A + (size_t)(m0 + row) * 4096 + kt + ks * 8),
                (lptr_t)(void*)(As + (size_t)cb * 8), 16, 0, 0);
            __builtin_amdgcn_global_load_lds(
                (gptr_t)(const void*)(B + (size_t)(n0 + row) * 4096 + kt + ks * 8),
                (lptr_t)(void*)(Bs + (size_t)cb * 8), 16, 0, 0);
        }
    };

    float4v acc[4][4];
    float4v z = {0.f, 0.f, 0.f, 0.f};
    #pragma unroll
    for (int i = 0; i < 4; i++)
        #pragma unroll
        for (int j = 0; j < 4; j++) acc[i][j] = z;

    const int nt = 4096 / 32;
    stage(0, 0); stage(1, 32);

    int ksw = lk ^ ((lr >> 1) & 3);
    int aoff = lr * 4 + ksw;

    for (int t = 0; t < nt; ++t) {
        if (t + 2 < nt) stage((t + 2) % 3, (t + 2) * 32);
        if (t + 2 < nt)      asm volatile("s_waitcnt vmcnt(8)" ::: "memory");
        else if (t + 1 < nt) asm volatile("s_waitcnt vmcnt(4)" ::: "memory");
        else                 asm volatile("s_waitcnt vmcnt(0)" ::: "memory");
        __builtin_amdgcn_s_barrier();
        asm volatile("" ::: "memory");
        const unsigned short* As = lds + (t % 3) * 8192;
        const unsigned short* Bs = As + 4096;
        short8v af[4], bfr[4];
        #pragma unroll
        for (int f = 0; f < 4; f++) {
            af[f]  = *(const short8v*)&As[((wm * 64 + f * 16) * 4 + aoff) * 8];
            bfr[f] = *(const short8v*)&Bs[((wn * 64 + f * 16) * 4 + aoff) * 8];
        }
        __builtin_amdgcn_s_setprio(1);
        #pragma unroll
        for (int mf = 0; mf < 4; mf++)
            #pragma unroll
            for (int nf = 0; nf < 4; nf++)
                acc[mf][nf] = __builtin_amdgcn_mfma_f32_16x16x32_bf16(
                    af[mf], bfr[nf], acc[mf][nf], 0, 0, 0);
        __builtin_amdgcn_s_setprio(0);
        asm volatile("" ::: "memory");
        __builtin_amdgcn_s_barrier();
    }

    int rbase = lk << 2;
    #pragma unroll
    for (int mf = 0; mf < 4; mf++) {
        #pragma unroll
        for (int q = 0; q < 4; q++) {
            int m = m0 + wm * 64 + mf * 16 + rbase + q;
            int tok = tokens[m];
            #pragma unroll
            for (int nf = 0; nf < 4; nf++) {
                int n = n0 + wn * 64 + nf * 16 + lr;
                float v = acc[mf][nf][q] + out_b[n] + embed_w[(size_t)tok * HID + n];
                Cout[(size_t)m * HID + n] = v;
            }
        }
    }
}

// ---------------- scan phase 1: per-chunk (A, H) from proj ----------------
__global__ __launch_bounds__(256) void scan_phase1(
    const unsigned short* __restrict__ proj,
    float* __restrict__ chunkA, float* __restrict__ chunkH)
{
    int bid = blockIdx.x;
    int sg = bid & 15, q = (bid >> 4) & 31, b = bid >> 9;
    int s = sg * 256 + threadIdx.x;
    int t0 = q * CHUNK;
    float Aa = 1.f, Hh = 0.f;
    const unsigned short* p = proj + (size_t)(b * LSEQ + t0) * 16384 + s;
    for (int t = 0; t < CHUNK; t++) {
        float xg = bf2f(p[0]);
        float al = bf2f(p[4096]);
        float bl = bf2f(p[8192]);
        float a = sigmoidf_(al);
        float bx = sigmoidf_(bl) * xg;
        Hh = fmaf(a, Hh, bx);
        Aa *= a;
        p += 16384;
    }
    int ch = b * STT + s;
    chunkA[ch * NCHUNK + q] = Aa;
    chunkH[ch * NCHUNK + q] = Hh;
}

__global__ __launch_bounds__(256) void scan_phase2(
    const float* __restrict__ chunkA, const float* __restrict__ chunkH,
    float* __restrict__ carry)
{
    int ch = blockIdx.x * 256 + threadIdx.x;
    float c = 0.f;
    for (int q = 0; q < NCHUNK; q++) {
        carry[ch * NCHUNK + q] = c;
        c = fmaf(chunkA[ch * NCHUNK + q], c, chunkH[ch * NCHUNK + q]);
    }
}

// ---------------- scan phase 3: h with carry, y = sig(c_l)*h (bf16) --------
__global__ __launch_bounds__(256) void scan_phase3(
    const unsigned short* __restrict__ proj, const float* __restrict__ carry,
    unsigned short* __restrict__ y)
{
    int bid = blockIdx.x;
    int sg = bid & 15, q = (bid >> 4) & 31, b = bid >> 9;
    int s = sg * 256 + threadIdx.x;
    int t0 = q * CHUNK;
    int ch = b * STT + s;
    float h = carry[ch * NCHUNK + q];
    const unsigned short* p = proj + (size_t)(b * LSEQ + t0) * 16384 + s;
    unsigned short* yp = y + (size_t)(b * LSEQ + t0) * STT + s;
    for (int t = 0; t < CHUNK; t++) {
        float xg = bf2f(p[0]);
        float al = bf2f(p[4096]);
        float bl = bf2f(p[8192]);
        float cl = bf2f(p[12288]);
        float a = sigmoidf_(al);
        float bx = sigmoidf_(bl) * xg;
        h = fmaf(a, h, bx);
        *yp = f2bf(sigmoidf_(cl) * h);
        p += 16384; yp += STT;
    }
}

// ---------------- head GEMM ----------------
__global__ __launch_bounds__(64) void head_kernel(
    const float* __restrict__ out, const float* __restrict__ head_w,
    const float* __restrict__ head_b, float* __restrict__ logits)
{
    __shared__ float row[HID];
    int m = blockIdx.x;
    int t = threadIdx.x;
    for (int i = t; i < HID / 4; i += 64)
        ((float4*)row)[i] = ((const float4*)(out + (size_t)m * HID))[i];
    __syncthreads();
    if (t < VOCAB) {
        float s = head_b[t];
        #pragma unroll 8
        for (int k = 0; k < HID; k++)
            s = fmaf(row[k], head_w[k * VOCAB + t], s);
        logits[m * VOCAB + t] = s;
    }
}

extern "C" void kernel_launch(void* const* d_in, const int* in_sizes, int n_in,
                              void* d_out, int out_size, void* d_ws, size_t ws_size,
                              hipStream_t stream) {
    const int*   tokens  = (const int*)d_in[0];
    const float* embed_w = (const float*)d_in[1];
    const float* norm_w  = (const float*)d_in[2];
    const float* in_w    = (const float*)d_in[3];
    const float* in_b    = (const float*)d_in[4];
    const float* out_w   = (const float*)d_in[5];
    const float* out_b   = (const float*)d_in[6];
    const float* head_w  = (const float*)d_in[7];
    const float* head_b  = (const float*)d_in[8];
    float* logits = (float*)d_out;

    char* w = (char*)d_ws;
    unsigned short* proj   = (unsigned short*)w;                    // 128 MiB
    unsigned short* y      = (unsigned short*)(w + 134217728);      // 32 MiB
    unsigned short* in_wT  = (unsigned short*)(w + 167772160);      // 32 MiB
    float*          outbuf = (float*)(w + 167772160);               // reuses in_wT (16 MiB)
    unsigned short* xn     = (unsigned short*)(w + 201326592);      // 8 MiB
    unsigned short* out_wT = (unsigned short*)(w + 201326592);      // reuses xn (8 MiB)
    float* chunkA = (float*)(w + 209715200);
    float* chunkH = chunkA + 8192 * NCHUNK;
    float* carry  = chunkH + 8192 * NCHUNK;

    hipLaunchKernelGGL(cast_transpose_kernel, dim3(16384 / 32, 1024 / 32), dim3(256), 0, stream,
                       in_w, in_wT, 1024, 16384);
    hipLaunchKernelGGL(embed_norm_kernel, dim3(MTOK), dim3(256), 0, stream,
                       tokens, embed_w, norm_w, xn);
    hipLaunchKernelGGL(gemm_in_mfma, dim3(1024), dim3(512), 131072, stream,
                       xn, in_wT, in_b, proj);
    hipLaunchKernelGGL(scan_phase1, dim3(1024), dim3(256), 0, stream,
                       proj, chunkA, chunkH);
    hipLaunchKernelGGL(scan_phase2, dim3(32), dim3(256), 0, stream,
                       chunkA, chunkH, carry);
    hipLaunchKernelGGL(scan_phase3, dim3(1024), dim3(256), 0, stream,
                       proj, carry, y);
    hipLaunchKernelGGL(cast_transpose_kernel, dim3(1024 / 32, 4096 / 32), dim3(256), 0, stream,
                       out_w, out_wT, 4096, 1024);
    hipLaunchKernelGGL(gemm_out_mfma, dim3(256), dim3(256), 49152, stream,
                       y, out_wT, out_b, tokens, embed_w, outbuf);
    hipLaunchKernelGGL(head_kernel, dim3(MTOK), dim3(64), 0, stream,
                       outbuf, head_w, head_b, logits);
}

// Round 8
// 355.998 us; speedup vs baseline: 1.3944x; 1.0179x over previous
//
#include <hip/hip_runtime.h>
#include <math.h>

#define HID   1024
#define STT   4096
#define MTOK  4096   // B*L
#define LSEQ  2048
#define NCHUNK 32
#define CHUNK  64
#define VOCAB  62

typedef __attribute__((ext_vector_type(8))) short short8v;
typedef __attribute__((ext_vector_type(4))) float float4v;

typedef const __attribute__((address_space(1))) void* gptr_t;
typedef __attribute__((address_space(3))) void* lptr_t;

__device__ __forceinline__ float sigmoidf_(float x) {
    return 1.0f / (1.0f + expf(-x));
}
__device__ __forceinline__ unsigned short f2bf(float f) {
    unsigned int u = __float_as_uint(f);
    unsigned int r = (u + 0x7fffu + ((u >> 16) & 1u)) >> 16;
    return (unsigned short)r;
}
__device__ __forceinline__ float bf2f(unsigned short b) {
    return __uint_as_float(((unsigned int)b) << 16);
}

// ---------------- cast + transpose: src[R][C] f32 -> dst[C][R] bf16 ----------
__global__ __launch_bounds__(256) void cast_transpose_kernel(
    const float* __restrict__ src, unsigned short* __restrict__ dst, int R, int C)
{
    __shared__ float tile[32][33];
    int c0 = blockIdx.x * 32, r0 = blockIdx.y * 32;
    int t = threadIdx.x;
    int r = t >> 3, c4 = (t & 7) << 2;
    float4 v = *(const float4*)(src + (size_t)(r0 + r) * C + c0 + c4);
    tile[r][c4 + 0] = v.x; tile[r][c4 + 1] = v.y;
    tile[r][c4 + 2] = v.z; tile[r][c4 + 3] = v.w;
    __syncthreads();
    int oc = t >> 3;
    int orr = (t & 7) << 2;
    ushort4 o;
    o.x = f2bf(tile[orr + 0][oc]); o.y = f2bf(tile[orr + 1][oc]);
    o.z = f2bf(tile[orr + 2][oc]); o.w = f2bf(tile[orr + 3][oc]);
    *(ushort4*)(dst + (size_t)(c0 + oc) * R + r0 + orr) = o;
}

// ---------------- embedding gather + RMSNorm -> bf16 ----------------
__global__ __launch_bounds__(256) void embed_norm_kernel(
    const int* __restrict__ tokens, const float* __restrict__ embed_w,
    const float* __restrict__ norm_w, unsigned short* __restrict__ xn)
{
    int m = blockIdx.x;
    int t = threadIdx.x;
    int tok = tokens[m];
    float4 x = ((const float4*)(embed_w + (size_t)tok * HID))[t];
    float ss = x.x * x.x + x.y * x.y + x.z * x.z + x.w * x.w;
    for (int off = 32; off > 0; off >>= 1) ss += __shfl_down(ss, off);
    __shared__ float wsum[4];
    if ((t & 63) == 0) wsum[t >> 6] = ss;
    __syncthreads();
    float tot = wsum[0] + wsum[1] + wsum[2] + wsum[3];
    float scale = rsqrtf(tot / (float)HID + 1e-6f);
    float4 w4 = ((const float4*)norm_w)[t];
    ushort4 o;
    o.x = f2bf(x.x * scale * w4.x); o.y = f2bf(x.y * scale * w4.y);
    o.z = f2bf(x.z * scale * w4.z); o.w = f2bf(x.w * scale * w4.w);
    *(ushort4*)(xn + (size_t)m * HID + (t << 2)) = o;
}

// ---------------- MFMA GEMM 1: proj = xn @ in_w + in_b  (bf16 out) ----------
// 256x256 tile, BK=64, 8 waves (2M x 4N), 2 LDS buffers (64 KiB each).
// Overlapped schedule, 1 barrier per K-tile:
//   STAGE_A(next) | ds_read set1(kk1) | MFMA set0 | STAGE_B(next) | MFMA set1
//   | __syncthreads (single vmcnt drain, covered by ~full iteration)
//   | ds_read set0 from next buffer (overlaps barrier stragglers + next stage).
// LDS per kk-half region: chunk p = row*4 + (ks ^ ((row>>1)&3))  — staging is
// coalesced (16 rows x 64B per instr), frag reads 2-way bank = conflict-free
// (measured 0 conflicts, rounds 5-6).
__global__ __launch_bounds__(512, 2) void gemm_in_mfma(
    const unsigned short* __restrict__ A, const unsigned short* __restrict__ B,
    const float* __restrict__ bias, unsigned short* __restrict__ Cout)
{
    extern __shared__ unsigned short lds[];   // 2 bufs * 32768 shorts = 128 KiB
    // buffer b layout (shorts): A_kk0[8192] A_kk1[8192] B_kk0[8192] B_kk1[8192]
    int tid = threadIdx.x;
    int wid = tid >> 6, lane = tid & 63;
    // XCD 2D-cell swizzle: xcd owns 4 by x 32 bx (by-fast) -> L2-resident panels
    int wg = blockIdx.x;
    int xcd = wg & 7, loc = wg >> 3;
    int by = ((xcd >> 1) << 2) + (loc & 3);   // 0..15
    int bx = ((xcd & 1) << 5) + (loc >> 2);   // 0..63
    int m0 = by * 256, n0 = bx * 256;
    int wm = wid >> 2, wn = wid & 3;
    int lr = lane & 15, lk = lane >> 4;

    // staging lane mapping (per kk-half: 256 rows x 4 chunks of 16B)
    int cb0 = wid * 64, cb1 = 512 + wid * 64;     // wave-uniform chunk bases
    int p0 = cb0 + lane, p1 = cb1 + lane;
    int row0 = p0 >> 2, ks0 = (p0 & 3) ^ ((row0 >> 1) & 3);
    int row1 = p1 >> 2, ks1 = (p1 & 3) ^ ((row1 >> 1) & 3);

    // stage one kk-half (16 KiB) of A (which=0) or B (which=1) into buffer b
#define SHALF(SRC, base0, b, which, kt, kk) do {                                 \
    unsigned short* _d = lds + (b) * 32768 + (which) * 16384 + (kk) * 8192;      \
    __builtin_amdgcn_global_load_lds(                                            \
        (gptr_t)(const void*)((SRC) + (size_t)((base0) + row0) * 1024 +          \
                              (kt) * 64 + (kk) * 32 + ks0 * 8),                  \
        (lptr_t)(void*)(_d + (size_t)cb0 * 8), 16, 0, 0);                        \
    __builtin_amdgcn_global_load_lds(                                            \
        (gptr_t)(const void*)((SRC) + (size_t)((base0) + row1) * 1024 +          \
                              (kt) * 64 + (kk) * 32 + ks1 * 8),                  \
        (lptr_t)(void*)(_d + (size_t)cb1 * 8), 16, 0, 0);                        \
} while (0)

    int ksw = lk ^ ((lr >> 1) & 3);

    // read one frag set (8 A + 4 B) for buffer b, kk-half kk
#define READSET(b, kk, AF, BF) do {                                              \
    const unsigned short* _ab = lds + (b) * 32768 + (kk) * 8192;                 \
    const unsigned short* _bb = _ab + 16384;                                     \
    _Pragma("unroll")                                                            \
    for (int mf = 0; mf < 8; mf++)                                               \
        (AF)[mf] = *(const short8v*)&_ab[(((wm * 128 + mf * 16 + lr) << 2) + ksw) * 8]; \
    _Pragma("unroll")                                                            \
    for (int nf = 0; nf < 4; nf++)                                               \
        (BF)[nf] = *(const short8v*)&_bb[(((wn * 64 + nf * 16 + lr) << 2) + ksw) * 8];  \
} while (0)

#define MFMACLUSTER(AF, BF) do {                                                 \
    __builtin_amdgcn_s_setprio(1);                                               \
    _Pragma("unroll")                                                            \
    for (int mf = 0; mf < 8; mf++)                                               \
        _Pragma("unroll")                                                        \
        for (int nf = 0; nf < 4; nf++)                                           \
            acc[mf][nf] = __builtin_amdgcn_mfma_f32_16x16x32_bf16(               \
                (AF)[mf], (BF)[nf], acc[mf][nf], 0, 0, 0);                       \
    __builtin_amdgcn_s_setprio(0);                                               \
} while (0)

    float4v acc[8][4];
    float4v z = {0.f, 0.f, 0.f, 0.f};
    #pragma unroll
    for (int i = 0; i < 8; i++)
        #pragma unroll
        for (int j = 0; j < 4; j++) acc[i][j] = z;

    // prologue: stage K-tile 0 fully into buffer 0, drain, read set0
    SHALF(A, m0, 0, 0, 0, 0); SHALF(A, m0, 0, 0, 0, 1);
    SHALF(B, n0, 0, 1, 0, 0); SHALF(B, n0, 0, 1, 0, 1);
    __syncthreads();

    short8v af0[8], af1[8], bf0[4], bf1[4];
    READSET(0, 0, af0, bf0);

    for (int kt = 0; kt < 16; ++kt) {
        int cur = kt & 1, nxt = cur ^ 1;
        if (kt < 15) { SHALF(A, m0, nxt, 0, kt + 1, 0); SHALF(A, m0, nxt, 0, kt + 1, 1); }
        READSET(cur, 1, af1, bf1);          // kk1 frags, overlap with MFMA set0
        MFMACLUSTER(af0, bf0);
        if (kt < 15) { SHALF(B, n0, nxt, 1, kt + 1, 0); SHALF(B, n0, nxt, 1, kt + 1, 1); }
        MFMACLUSTER(af1, bf1);
        __syncthreads();                    // single drain per K-tile (long cover)
        if (kt < 15) READSET(nxt, 0, af0, bf0);   // next tile's kk0 frags
    }

    int rbase = lk << 2;
    #pragma unroll
    for (int mf = 0; mf < 8; mf++)
        #pragma unroll
        for (int nf = 0; nf < 4; nf++) {
            int n = n0 + wn * 64 + nf * 16 + lr;
            float bv = bias[n];
            #pragma unroll
            for (int q = 0; q < 4; q++) {
                int m = m0 + wm * 128 + mf * 16 + rbase + q;
                Cout[(size_t)m * 16384 + n] = f2bf(acc[mf][nf][q] + bv);
            }
        }
#undef SHALF
#undef READSET
#undef MFMACLUSTER
}

// ---------------- MFMA GEMM 2: out = y @ out_w + out_b + residual (f32 out) --
// 128x128 tile, BK=32, 4 waves (2x2), 3-buffer depth-2 pipeline, chunk swizzle.
__global__ __launch_bounds__(256, 3) void gemm_out_mfma(
    const unsigned short* __restrict__ A, const unsigned short* __restrict__ B,
    const float* __restrict__ out_b, const int* __restrict__ tokens,
    const float* __restrict__ embed_w, float* __restrict__ Cout)
{
    extern __shared__ unsigned short lds[];   // 3 bufs * (4096 A + 4096 B) = 48 KiB
    int tid = threadIdx.x;
    int wid = tid >> 6, lane = tid & 63;
    int wg = blockIdx.x;                      // 256 WGs: 8 n-tiles x 32 m-tiles
    int swz = (wg & 7) * 32 + (wg >> 3);
    int bx = swz & 7;
    int by = swz >> 3;
    int m0 = by * 128, n0 = bx * 128;
    int wm = wid >> 1, wn = wid & 1;
    int lr = lane & 15, lk = lane >> 4;

    auto stage = [&](int b, int kt) {
        unsigned short* As = lds + b * 8192;
        unsigned short* Bs = As + 4096;
        #pragma unroll
        for (int i = 0; i < 2; i++) {
            int cb = i * 256 + wid * 64;
            int p = cb + lane;
            int row = p >> 2;
            int ks = (p & 3) ^ ((row >> 1) & 3);
            __builtin_amdgcn_global_load_lds(
                (gptr_t)(const void*)(A + (size_t)(m0 + row) * 4096 + kt + ks * 8),
                (lptr_t)(void*)(As + (size_t)cb * 8), 16, 0, 0);
            __builtin_amdgcn_global_load_lds(
                (gptr_t)(const void*)(B + (size_t)(n0 + row) * 4096 + kt + ks * 8),
                (lptr_t)(void*)(Bs + (size_t)cb * 8), 16, 0, 0);
        }
    };

    float4v acc[4][4];
    float4v z = {0.f, 0.f, 0.f, 0.f};
    #pragma unroll
    for (int i = 0; i < 4; i++)
        #pragma unroll
        for (int j = 0; j < 4; j++) acc[i][j] = z;

    const int nt = 4096 / 32;
    stage(0, 0); stage(1, 32);

    int ksw = lk ^ ((lr >> 1) & 3);
    int aoff = lr * 4 + ksw;

    for (int t = 0; t < nt; ++t) {
        if (t + 2 < nt) stage((t + 2) % 3, (t + 2) * 32);
        if (t + 2 < nt)      asm volatile("s_waitcnt vmcnt(8)" ::: "memory");
        else if (t + 1 < nt) asm volatile("s_waitcnt vmcnt(4)" ::: "memory");
        else                 asm volatile("s_waitcnt vmcnt(0)" ::: "memory");
        __builtin_amdgcn_s_barrier();
        asm volatile("" ::: "memory");
        const unsigned short* As = lds + (t % 3) * 8192;
        const unsigned short* Bs = As + 4096;
        short8v af[4], bfr[4];
        #pragma unroll
        for (int f = 0; f < 4; f++) {
            af[f]  = *(const short8v*)&As[((wm * 64 + f * 16) * 4 + aoff) * 8];
            bfr[f] = *(const short8v*)&Bs[((wn * 64 + f * 16) * 4 + aoff) * 8];
        }
        __builtin_amdgcn_s_setprio(1);
        #pragma unroll
        for (int mf = 0; mf < 4; mf++)
            #pragma unroll
            for (int nf = 0; nf < 4; nf++)
                acc[mf][nf] = __builtin_amdgcn_mfma_f32_16x16x32_bf16(
                    af[mf], bfr[nf], acc[mf][nf], 0, 0, 0);
        __builtin_amdgcn_s_setprio(0);
        asm volatile("" ::: "memory");
        __builtin_amdgcn_s_barrier();
    }

    int rbase = lk << 2;
    #pragma unroll
    for (int mf = 0; mf < 4; mf++) {
        #pragma unroll
        for (int q = 0; q < 4; q++) {
            int m = m0 + wm * 64 + mf * 16 + rbase + q;
            int tok = tokens[m];
            #pragma unroll
            for (int nf = 0; nf < 4; nf++) {
                int n = n0 + wn * 64 + nf * 16 + lr;
                float v = acc[mf][nf][q] + out_b[n] + embed_w[(size_t)tok * HID + n];
                Cout[(size_t)m * HID + n] = v;
            }
        }
    }
}

// ---------------- scan phase 1: per-chunk (A, H) from proj ----------------
__global__ __launch_bounds__(256) void scan_phase1(
    const unsigned short* __restrict__ proj,
    float* __restrict__ chunkA, float* __restrict__ chunkH)
{
    int bid = blockIdx.x;
    int sg = bid & 15, q = (bid >> 4) & 31, b = bid >> 9;
    int s = sg * 256 + threadIdx.x;
    int t0 = q * CHUNK;
    float Aa = 1.f, Hh = 0.f;
    const unsigned short* p = proj + (size_t)(b * LSEQ + t0) * 16384 + s;
    for (int t = 0; t < CHUNK; t++) {
        float xg = bf2f(p[0]);
        float al = bf2f(p[4096]);
        float bl = bf2f(p[8192]);
        float a = sigmoidf_(al);
        float bx = sigmoidf_(bl) * xg;
        Hh = fmaf(a, Hh, bx);
        Aa *= a;
        p += 16384;
    }
    int ch = b * STT + s;
    chunkA[ch * NCHUNK + q] = Aa;
    chunkH[ch * NCHUNK + q] = Hh;
}

__global__ __launch_bounds__(256) void scan_phase2(
    const float* __restrict__ chunkA, const float* __restrict__ chunkH,
    float* __restrict__ carry)
{
    int ch = blockIdx.x * 256 + threadIdx.x;
    float c = 0.f;
    for (int q = 0; q < NCHUNK; q++) {
        carry[ch * NCHUNK + q] = c;
        c = fmaf(chunkA[ch * NCHUNK + q], c, chunkH[ch * NCHUNK + q]);
    }
}

// ---------------- scan phase 3: h with carry, y = sig(c_l)*h (bf16) --------
__global__ __launch_bounds__(256) void scan_phase3(
    const unsigned short* __restrict__ proj, const float* __restrict__ carry,
    unsigned short* __restrict__ y)
{
    int bid = blockIdx.x;
    int sg = bid & 15, q = (bid >> 4) & 31, b = bid >> 9;
    int s = sg * 256 + threadIdx.x;
    int t0 = q * CHUNK;
    int ch = b * STT + s;
    float h = carry[ch * NCHUNK + q];
    const unsigned short* p = proj + (size_t)(b * LSEQ + t0) * 16384 + s;
    unsigned short* yp = y + (size_t)(b * LSEQ + t0) * STT + s;
    for (int t = 0; t < CHUNK; t++) {
        float xg = bf2f(p[0]);
        float al = bf2f(p[4096]);
        float bl = bf2f(p[8192]);
        float cl = bf2f(p[12288]);
        float a = sigmoidf_(al);
        float bx = sigmoidf_(bl) * xg;
        h = fmaf(a, h, bx);
        *yp = f2bf(sigmoidf_(cl) * h);
        p += 16384; yp += STT;
    }
}

// ---------------- head GEMM ----------------
__global__ __launch_bounds__(64) void head_kernel(
    const float* __restrict__ out, const float* __restrict__ head_w,
    const float* __restrict__ head_b, float* __restrict__ logits)
{
    __shared__ float row[HID];
    int m = blockIdx.x;
    int t = threadIdx.x;
    for (int i = t; i < HID / 4; i += 64)
        ((float4*)row)[i] = ((const float4*)(out + (size_t)m * HID))[i];
    __syncthreads();
    if (t < VOCAB) {
        float s = head_b[t];
        #pragma unroll 8
        for (int k = 0; k < HID; k++)
            s = fmaf(row[k], head_w[k * VOCAB + t], s);
        logits[m * VOCAB + t] = s;
    }
}

extern "C" void kernel_launch(void* const* d_in, const int* in_sizes, int n_in,
                              void* d_out, int out_size, void* d_ws, size_t ws_size,
                              hipStream_t stream) {
    const int*   tokens  = (const int*)d_in[0];
    const float* embed_w = (const float*)d_in[1];
    const float* norm_w  = (const float*)d_in[2];
    const float* in_w    = (const float*)d_in[3];
    const float* in_b    = (const float*)d_in[4];
    const float* out_w   = (const float*)d_in[5];
    const float* out_b   = (const float*)d_in[6];
    const float* head_w  = (const float*)d_in[7];
    const float* head_b  = (const float*)d_in[8];
    float* logits = (float*)d_out;

    char* w = (char*)d_ws;
    unsigned short* proj   = (unsigned short*)w;                    // 128 MiB
    unsigned short* y      = (unsigned short*)(w + 134217728);      // 32 MiB
    unsigned short* in_wT  = (unsigned short*)(w + 167772160);      // 32 MiB
    float*          outbuf = (float*)(w + 167772160);               // reuses in_wT (16 MiB)
    unsigned short* xn     = (unsigned short*)(w + 201326592);      // 8 MiB
    unsigned short* out_wT = (unsigned short*)(w + 201326592);      // reuses xn (8 MiB)
    float* chunkA = (float*)(w + 209715200);
    float* chunkH = chunkA + 8192 * NCHUNK;
    float* carry  = chunkH + 8192 * NCHUNK;

    hipLaunchKernelGGL(cast_transpose_kernel, dim3(16384 / 32, 1024 / 32), dim3(256), 0, stream,
                       in_w, in_wT, 1024, 16384);
    hipLaunchKernelGGL(embed_norm_kernel, dim3(MTOK), dim3(256), 0, stream,
                       tokens, embed_w, norm_w, xn);
    hipLaunchKernelGGL(gemm_in_mfma, dim3(1024), dim3(512), 131072, stream,
                       xn, in_wT, in_b, proj);
    hipLaunchKernelGGL(scan_phase1, dim3(1024), dim3(256), 0, stream,
                       proj, chunkA, chunkH);
    hipLaunchKernelGGL(scan_phase2, dim3(32), dim3(256), 0, stream,
                       chunkA, chunkH, carry);
    hipLaunchKernelGGL(scan_phase3, dim3(1024), dim3(256), 0, stream,
                       proj, carry, y);
    hipLaunchKernelGGL(cast_transpose_kernel, dim3(1024 / 32, 4096 / 32), dim3(256), 0, stream,
                       out_w, out_wT, 4096, 1024);
    hipLaunchKernelGGL(gemm_out_mfma, dim3(256), dim3(256), 49152, stream,
                       y, out_wT, out_b, tokens, embed_w, outbuf);
    hipLaunchKernelGGL(head_kernel, dim3(MTOK), dim3(64), 0, stream,
                       outbuf, head_w, head_b, logits);
}